// Round 1
// baseline (1931.366 us; speedup 1.0000x reference)
//
#include <hip/hip_runtime.h>
#include <math.h>

// Persistent cooperative resonator-network decoder for MI355X (gfx950).
// 256 blocks (1 per CU) x 1024 threads. Codebook cos/sin lives entirely in LDS
// (dim-sliced: 16 dims per CU -> 32*1024*4B = 128 KiB). One grid barrier per
// iteration; cross-CU sims reduction via native fp32 global atomics into a
// 3-deep rotating buffer. No trig inside the loop (cos(atan2(im,re)) = re/|z|).

#define NBLK  256
#define NTHR  1024
#define KCODES 1024
#define DIMS  4096
#define BATCH 8
#define DPC   16          // dims per CU
#define COMPS 32          // 2*DPC interleaved (cos,sin)

// ---- DPP wave64 sum: result valid in lane 63 ----
template <int CTRL>
__device__ __forceinline__ float dpp_add(float x) {
  int v = __builtin_amdgcn_update_dpp(0, __float_as_int(x), CTRL, 0xF, 0xF, false);
  return x + __int_as_float(v);
}
__device__ __forceinline__ float wave_sum64(float x) {
  x = dpp_add<0x111>(x);   // row_shr:1
  x = dpp_add<0x112>(x);   // row_shr:2
  x = dpp_add<0x114>(x);   // row_shr:4
  x = dpp_add<0x118>(x);   // row_shr:8
  x = dpp_add<0x142>(x);   // row_bcast:15
  x = dpp_add<0x143>(x);   // row_bcast:31
  return x;                // lane 63 = sum of all 64 lanes
}

__device__ __forceinline__ void grid_barrier(unsigned* cnt, unsigned target) {
  __syncthreads();
  if (threadIdx.x == 0) {
    __threadfence();  // agent-scope release: flush this XCD's writes
    __hip_atomic_fetch_add(cnt, 1u, __ATOMIC_RELEASE, __HIP_MEMORY_SCOPE_AGENT);
    while (__hip_atomic_load(cnt, __ATOMIC_ACQUIRE, __HIP_MEMORY_SCOPE_AGENT) < target) {
      __builtin_amdgcn_s_sleep(2);
    }
  }
  __syncthreads();
}

__global__ __launch_bounds__(NTHR) void resonator_kernel(
    const float* __restrict__ superposed,   // (8,4096)
    const float* __restrict__ codebook,     // (1024,4096) angles
    const int*  __restrict__ nit_p,         // num_iterations (scalar)
    float* __restrict__ out,                // (8,1024)
    float* __restrict__ ws)
{
  // LDS: 131072 + 32768 = 163840 B = full 160 KiB.
  __shared__ float cbT[COMPS][KCODES];      // [comp][code]; comp = 2*d + (0=cos,1=sin)
  __shared__ float wbuf[BATCH][KCODES];     // softmax weights; aliased as scratch

  float*    bufs  = ws;                                  // 3 * 8192 raw-sum buffers
  unsigned* cnt   = (unsigned*)(ws + 3*BATCH*KCODES);    // barrier counter
  float*    est_g = ws + 3*BATCH*KCODES + 32;            // 256 floats per block

  const int t    = threadIdx.x;          // == code index for phase A / softmax
  const int bid  = blockIdx.x;
  const int lane = t & 63;
  const int wv   = t >> 6;
  const int d0   = bid * DPC;
  float* est_me  = est_g + bid * (BATCH * COMPS);
  const int NI   = *nit_p;               // 50

  // ---------------- init: codebook trig -> LDS, est from superposed ----------
  {
    const float* crow = codebook + (size_t)t * DIMS + d0;
    #pragma unroll
    for (int j = 0; j < DPC; ++j) {
      float a = crow[j], s, c;
      sincosf(a, &s, &c);
      cbT[2*j + 0][t] = c;
      cbT[2*j + 1][t] = s;
    }
    if (t < BATCH * DPC) {               // 128 threads init est slice
      int b = t >> 4, d = t & 15;
      float a = superposed[b * DIMS + d0 + d], s, c;
      sincosf(a, &s, &c);
      est_me[b * COMPS + 2*d + 0] = c;
      est_me[b * COMPS + 2*d + 1] = s;
    }
  }
  __syncthreads();

  unsigned barnum = 0;
  for (int it = 0; ; ++it) {
    // ================= PHASE A: partial sims over this CU's 16 dims =========
    // Each wave holds the full 256-float est slice distributed 4/lane;
    // scalar broadcast via v_readlane (compile-time lane indices).
    float4 ve = *(const float4*)(est_me + 4 * lane);
    float acc[BATCH];
    #pragma unroll
    for (int b = 0; b < BATCH; ++b) acc[b] = 0.0f;

    #pragma unroll
    for (int comp = 0; comp < COMPS; ++comp) {
      const float cv = cbT[comp][t];
      #pragma unroll
      for (int b = 0; b < BATCH; ++b) {
        const int idx = b * COMPS + comp;
        const int sl  = idx >> 2;
        const int jj  = idx & 3;
        const float vsrc = (jj == 0) ? ve.x : (jj == 1) ? ve.y : (jj == 2) ? ve.z : ve.w;
        const float ev = __int_as_float(__builtin_amdgcn_readlane(__float_as_int(vsrc), sl));
        acc[b] = fmaf(ev, cv, acc[b]);
      }
    }

    if (it == NI) {
      // Final pass: output mean cosine directly (d_out pre-zeroed).
      const float sc = 1.0f / (float)DIMS;
      #pragma unroll
      for (int b = 0; b < BATCH; ++b)
        unsafeAtomicAdd(out + b * KCODES + t, acc[b] * sc);
      break;
    } else {
      float* tgt = bufs + (it % 3) * (BATCH * KCODES);
      #pragma unroll
      for (int b = 0; b < BATCH; ++b)
        unsafeAtomicAdd(tgt + b * KCODES + t, acc[b]);
    }

    grid_barrier(cnt, (++barnum) * NBLK);

    // ================= PHASE B =============================================
    // --- softmax over K (redundant per CU). arg = S * 10/4096 in [-10,10]:
    // no max-subtraction needed for fp32 safety.
    const float* src = bufs + (it % 3) * (BATCH * KCODES);
    const float k2 = (10.0f / 4096.0f) * 1.4426950408889634f;  // * log2(e)
    float e[BATCH];
    #pragma unroll
    for (int b = 0; b < BATCH; ++b)
      e[b] = exp2f(src[b * KCODES + t] * k2);

    float* smscr = &wbuf[0][0];          // [16 waves][8] partial sums + [128..136) Zinv
    #pragma unroll
    for (int b = 0; b < BATCH; ++b) {
      float s = wave_sum64(e[b]);
      if (lane == 63) smscr[wv * BATCH + b] = s;
    }
    __syncthreads();
    if (t < BATCH) {
      float z = 0.0f;
      #pragma unroll
      for (int k = 0; k < NTHR / 64; ++k) z += smscr[k * BATCH + t];
      smscr[128 + t] = 1.0f / z;
    }
    __syncthreads();
    float zin[BATCH];
    #pragma unroll
    for (int b = 0; b < BATCH; ++b) zin[b] = smscr[128 + b];
    __syncthreads();                      // everyone has Zinv before overwriting scratch
    #pragma unroll
    for (int b = 0; b < BATCH; ++b)
      wbuf[b][t] = e[b] * zin[b];
    __syncthreads();

    // --- GEMM: re/im[b][comp] = sum_c w[b][c] * cbT[comp][c]
    // thread = (cg: 8 comps) x (cc: 4 codes) x all 8 batches.
    const int cg = t >> 8;               // 0..3
    const int cc = t & 255;              // codes [4cc, 4cc+4)
    float w4[BATCH][4];
    #pragma unroll
    for (int b = 0; b < BATCH; ++b) {
      float4 tmp = *(const float4*)&wbuf[b][4 * cc];
      w4[b][0] = tmp.x; w4[b][1] = tmp.y; w4[b][2] = tmp.z; w4[b][3] = tmp.w;
    }
    __syncthreads();                      // w consumed -> wbuf becomes reduce scratch
    float* red = &wbuf[0][0];             // [16 waves][64]

    #pragma unroll
    for (int h = 0; h < 2; ++h) {
      const int comp0 = cg * 8 + h * 4;
      float4 cb4[4];
      #pragma unroll
      for (int c4 = 0; c4 < 4; ++c4)
        cb4[c4] = *(const float4*)&cbT[comp0 + c4][4 * cc];
      float a2[BATCH][4];
      #pragma unroll
      for (int b = 0; b < BATCH; ++b)
        #pragma unroll
        for (int c4 = 0; c4 < 4; ++c4) a2[b][c4] = 0.0f;

      #pragma unroll
      for (int c = 0; c < 4; ++c) {
        #pragma unroll
        for (int b = 0; b < BATCH; ++b) {
          const float wv_ = w4[b][c];
          #pragma unroll
          for (int c4 = 0; c4 < 4; ++c4) {
            const float cbv = (c == 0) ? cb4[c4].x : (c == 1) ? cb4[c4].y
                            : (c == 2) ? cb4[c4].z : cb4[c4].w;
            a2[b][c4] = fmaf(wv_, cbv, a2[b][c4]);
          }
        }
      }
      #pragma unroll
      for (int b = 0; b < BATCH; ++b) {
        #pragma unroll
        for (int c4 = 0; c4 < 4; ++c4) {
          float s = wave_sum64(a2[b][c4]);
          if (lane == 63) red[wv * 64 + h * 32 + b * 4 + c4] = s;
        }
      }
    }
    __syncthreads();

    // --- est update: cos(theta)=re/|z|, sin(theta)=im/|z| (no atan2 needed)
    if (t < BATCH * DPC) {
      const int b = t >> 4, d = t & 15;
      const int cR = 2 * d, cI = 2 * d + 1;
      float re = 0.0f, im = 0.0f;
      #pragma unroll
      for (int k = 0; k < 4; ++k) {
        re += red[(4 * (cR >> 3) + k) * 64 + ((cR & 7) >> 2) * 32 + b * 4 + (cR & 3)];
        im += red[(4 * (cI >> 3) + k) * 64 + ((cI & 7) >> 2) * 32 + b * 4 + (cI & 3)];
      }
      const float n2 = fmaf(re, re, im * im);
      float ec, es;
      if (n2 > 0.0f) {
        const float inv = rsqrtf(n2);
        ec = re * inv; es = im * inv;
      } else {                            // atan2(0,0) = 0
        ec = 1.0f; es = 0.0f;
      }
      est_me[b * COMPS + cR] = ec;
      est_me[b * COMPS + cI] = es;
    }

    // --- zero the buffer needed two iterations ahead (race-free: ordered by
    // the NEXT grid barrier before anyone accumulates into it).
    {
      float* zb = bufs + ((it + 2) % 3) * (BATCH * KCODES);
      #pragma unroll
      for (int b = 0; b < BATCH; ++b) zb[b * KCODES + t] = 0.0f;
    }
    __syncthreads();                      // est_me visible to all waves of this CU
  }
}

extern "C" void kernel_launch(void* const* d_in, const int* in_sizes, int n_in,
                              void* d_out, int out_size, void* d_ws, size_t ws_size,
                              hipStream_t stream) {
  const float* sup = (const float*)d_in[0];
  const float* cbk = (const float*)d_in[1];
  const int*   nit = (const int*)d_in[2];
  float* outp = (float*)d_out;
  float* ws   = (float*)d_ws;

  // Zero: 3 sims buffers (96 KiB) + barrier counter/pad (128 B), and d_out
  // (accumulated atomically by the final pass). Graph-capture safe.
  hipMemsetAsync(d_ws, 0, (3 * BATCH * KCODES + 32) * sizeof(float), stream);
  hipMemsetAsync(d_out, 0, (size_t)out_size * sizeof(float), stream);

  void* args[] = { (void*)&sup, (void*)&cbk, (void*)&nit, (void*)&outp, (void*)&ws };
  hipLaunchCooperativeKernel((const void*)resonator_kernel,
                             dim3(NBLK), dim3(NTHR), args, 0, stream);
}